// Round 1
// baseline (233.926 us; speedup 1.0000x reference)
//
#include <hip/hip_runtime.h>
#include <math.h>

// Problem constants (from reference): B=256, N=256, E=512, ITER=10
#define Bb   256
#define Nn   256
#define Ee   512
#define TK   32          // K-chunk staged in LDS per step
#define NCH  (Ee / TK)   // 16 chunks
#define NITER 10
#define LDST 260         // LDS row stride in floats: 260*4B = 1040B, 16B-aligned rows,
                         // 260 % 32 == 4 -> staging writes spread over 16 banks (<=4-way)

// One block per batch. 1024 threads = 32x32 grid; thread (tr,tc) owns the 8x8
// C-subtile rows [tr*8, tr*8+8) x cols [tc*8, tc*8+8).  P[b] (256x256 fp32)
// lives entirely in registers (64/thread), so the 10 CRF iterations never
// touch HBM for P.  Row norms come free as the diagonal of C = F F^T.
__global__ __launch_bounds__(1024) void crf_fused(
    const float* __restrict__ feats,   // [B, N, E]
    const float* __restrict__ logits,  // [B, N, 1]
    const float* __restrict__ W,       // [1, N, N]
    float* __restrict__ out)           // [B, N, 1]
{
    const int b  = blockIdx.x;
    const int t  = threadIdx.x;
    const int tr = t >> 5;      // 0..31
    const int tc = t & 31;      // 0..31
    const int r0 = tr * 8;
    const int c0 = tc * 8;

    __shared__ float ldsT[TK * LDST];  // transposed chunk: ldsT[k][n] = F[n][k0+k]
    __shared__ float norms[Nn];
    __shared__ float svec[Nn];
    __shared__ float lgv[Nn];
    __shared__ float uvec[Nn];

    float acc[8][8];
#pragma unroll
    for (int i = 0; i < 8; ++i)
#pragma unroll
        for (int j = 0; j < 8; ++j) acc[i][j] = 0.f;

    const float* Fb = feats + (size_t)b * Nn * Ee;

    // ---- GEMM: C = F F^T (256x256, K=512), K tiled by TK ----
    for (int ch = 0; ch < NCH; ++ch) {
        __syncthreads();   // previous chunk's reads done before overwrite
        {
            // stage transposed: each thread 2x float4 (coalesced: 16 lanes x 16B)
            const int ks = (t & 7) * 4;   // 0,4,...,28
            const int nb = t >> 3;        // 0..127
#pragma unroll
            for (int it = 0; it < 2; ++it) {
                const int n = nb + 128 * it;
                const float4 v = *reinterpret_cast<const float4*>(
                    Fb + (size_t)n * Ee + ch * TK + ks);
                ldsT[(ks + 0) * LDST + n] = v.x;
                ldsT[(ks + 1) * LDST + n] = v.y;
                ldsT[(ks + 2) * LDST + n] = v.z;
                ldsT[(ks + 3) * LDST + n] = v.w;
            }
        }
        __syncthreads();

#pragma unroll 4
        for (int kk = 0; kk < TK; ++kk) {
            const float* row = &ldsT[kk * LDST];
            // a: broadcast b128 x2 (same addr across lanes); b: contiguous b128 x2
            const float4 av0 = *reinterpret_cast<const float4*>(row + r0);
            const float4 av1 = *reinterpret_cast<const float4*>(row + r0 + 4);
            const float4 bv0 = *reinterpret_cast<const float4*>(row + c0);
            const float4 bv1 = *reinterpret_cast<const float4*>(row + c0 + 4);
            const float a0[8] = {av0.x, av0.y, av0.z, av0.w, av1.x, av1.y, av1.z, av1.w};
            const float b0[8] = {bv0.x, bv0.y, bv0.z, bv0.w, bv1.x, bv1.y, bv1.z, bv1.w};
#pragma unroll
            for (int i = 0; i < 8; ++i)
#pragma unroll
                for (int j = 0; j < 8; ++j)
                    acc[i][j] = fmaf(a0[i], b0[j], acc[i][j]);
        }
    }

    // ---- norms from the diagonal: thread (tr==tc) owns C[r][r] for its 8 rows ----
    if (tr == tc) {
#pragma unroll
        for (int i = 0; i < 8; ++i) norms[r0 + i] = sqrtf(acc[i][i]);
    }
    // init lg / unary
    if (t < Nn) {
        const float u = logits[(size_t)b * Nn + t];
        uvec[t] = u;
        lgv[t]  = u;
    }
    __syncthreads();

    // ---- P = (C / (norm_n*norm_m)) * 0.5*(W[n][m]+W[m][n]), in registers ----
#pragma unroll
    for (int i = 0; i < 8; ++i) {
        const int r = r0 + i;
        const float inr = 1.f / norms[r];
#pragma unroll
        for (int j = 0; j < 8; ++j) {
            const int c = c0 + j;
            const float wsym = 0.5f * (W[r * Nn + c] + W[c * Nn + r]);
            acc[i][j] = acc[i][j] * inr * (1.f / norms[c]) * wsym;
        }
    }
    __syncthreads();

    // ---- 10 mean-field iterations, all in LDS/registers ----
    for (int itr = 0; itr < NITER; ++itr) {
        if (t < Nn) {
            const float x = lgv[t];
            svec[t] = 2.f / (1.f + expf(-x)) - 1.f;   // 2*sigmoid(x)-1
        }
        __syncthreads();

        float e[8];
#pragma unroll
        for (int i = 0; i < 8; ++i) e[i] = 0.f;
#pragma unroll
        for (int j = 0; j < 8; ++j) {
            const float s = svec[c0 + j];
#pragma unroll
            for (int i = 0; i < 8; ++i) e[i] = fmaf(s, acc[i][j], e[i]);
        }
        // butterfly reduce across tc (lane bits 0..4 -> stays within 32-lane half)
#pragma unroll
        for (int off = 16; off >= 1; off >>= 1) {
#pragma unroll
            for (int i = 0; i < 8; ++i) e[i] += __shfl_xor(e[i], off);
        }
        if (tc == 0) {
#pragma unroll
            for (int i = 0; i < 8; ++i) lgv[r0 + i] = uvec[r0 + i] + e[i];
        }
        __syncthreads();
    }

    if (t < Nn) out[(size_t)b * Nn + t] = lgv[t];
}

extern "C" void kernel_launch(void* const* d_in, const int* in_sizes, int n_in,
                              void* d_out, int out_size, void* d_ws, size_t ws_size,
                              hipStream_t stream) {
    const float* feats  = (const float*)d_in[0];
    const float* logits = (const float*)d_in[1];
    const float* W      = (const float*)d_in[2];
    float* out = (float*)d_out;

    crf_fused<<<dim3(Bb), dim3(1024), 0, stream>>>(feats, logits, W, out);
}

// Round 2
// 100.506 us; speedup vs baseline: 2.3275x; 2.3275x over previous
//
#include <hip/hip_runtime.h>
#include <math.h>

// B=256, N=256, E=512, ITER=10
#define Bb   256
#define Nn   256
#define Ee   512
#define TK   128            // K-chunk (bf16) staged in LDS
#define NCH  (Ee / TK)      // 4 chunks
#define KST  (TK / 32)      // 4 mfma k-steps per chunk (K=32 each)
#define NITER 10

typedef __attribute__((ext_vector_type(8))) short bf16x8;   // 8 bf16 = 4 VGPR (MFMA A/B frag)
typedef __attribute__((ext_vector_type(4))) float f32x4;    // MFMA C/D frag

static __device__ __forceinline__ unsigned short f2bf(float f) {
    unsigned u = __float_as_uint(f);
    unsigned r = (u + 0x7FFFu + ((u >> 16) & 1u)) >> 16;    // RNE
    return (unsigned short)r;
}

// LDS tile: bf16 [256 rows][128 k], row stride 256B, XOR-swizzled (T2 st-style):
// byte ^= (row&7)<<4  -> strided per-row b128 reads spread across 8 16B slots.
static __device__ __forceinline__ int tile_byte(int row, int kelem) {
    int byteoff = row * 256 + kelem * 2;
    return byteoff ^ ((row & 7) << 4);
}

__global__ __launch_bounds__(1024, 4) void crf_mfma(
    const float* __restrict__ feats,   // [B, N, E]
    const float* __restrict__ logits,  // [B, N, 1]
    const float* __restrict__ W,       // [1, N, N]
    float* __restrict__ out)           // [B, N, 1]
{
    const int b    = blockIdx.x;
    const int t    = threadIdx.x;
    const int wave = t >> 6;           // 0..15
    const int lane = t & 63;
    const int wr   = wave >> 2;        // wave tile row (64-row block)
    const int wc   = wave & 3;         // wave tile col (64-col block)
    const int lo   = lane & 15;        // subtile col index (C/D: col = lane&15)
    const int hi   = lane >> 4;        // 0..3 (C/D: row = hi*4 + reg; A/B: k-base = hi*8)

    __shared__ unsigned char tileb[Nn * 256];   // 64 KB bf16 tile
    __shared__ float norms[Nn];
    __shared__ float invn[Nn];
    __shared__ float svec[Nn];
    __shared__ float uvec[Nn];
    __shared__ float lgv[Nn];
    __shared__ float part[4][Nn];

    f32x4 acc[4][4];
#pragma unroll
    for (int i = 0; i < 4; ++i)
#pragma unroll
        for (int j = 0; j < 4; ++j) acc[i][j] = (f32x4){0.f, 0.f, 0.f, 0.f};

    const float* Fb = feats + (size_t)b * Nn * Ee;

    // ================= GEMM: C = F F^T via bf16 MFMA =================
    for (int ch = 0; ch < NCH; ++ch) {
        __syncthreads();   // prior chunk's reads done before overwrite
        // ---- stage fp32 -> bf16 into swizzled LDS tile ----
#pragma unroll
        for (int it = 0; it < 8; ++it) {
            const int flat = it * 1024 + t;
            const int n  = flat >> 5;          // row 0..255
            const int c4 = flat & 31;          // float4 col 0..31
            const float4 v = *reinterpret_cast<const float4*>(
                Fb + (size_t)n * Ee + ch * TK + c4 * 4);
            ushort4 pk;
            pk.x = f2bf(v.x); pk.y = f2bf(v.y); pk.z = f2bf(v.z); pk.w = f2bf(v.w);
            // 8B write stays within one 16B xor granule (c4*8 is 8-aligned)
            *reinterpret_cast<ushort4*>(tileb + tile_byte(n, c4 * 4)) = pk;
        }
        __syncthreads();

        // ---- MFMA over this chunk ----
#pragma unroll
        for (int ks = 0; ks < KST; ++ks) {
            const int kb = ks * 32 + hi * 8;   // bf16 k index for this lane's frag
            bf16x8 af[4], bfv[4];
#pragma unroll
            for (int rb = 0; rb < 4; ++rb)
                af[rb] = *reinterpret_cast<const bf16x8*>(
                    tileb + tile_byte(wr * 64 + rb * 16 + lo, kb));
            if (wr == wc) {
#pragma unroll
                for (int cb = 0; cb < 4; ++cb) bfv[cb] = af[cb];
            } else {
#pragma unroll
                for (int cb = 0; cb < 4; ++cb)
                    bfv[cb] = *reinterpret_cast<const bf16x8*>(
                        tileb + tile_byte(wc * 64 + cb * 16 + lo, kb));
            }
#pragma unroll
            for (int rb = 0; rb < 4; ++rb)
#pragma unroll
                for (int cb = 0; cb < 4; ++cb)
                    acc[rb][cb] = __builtin_amdgcn_mfma_f32_16x16x32_bf16(
                        af[rb], bfv[cb], acc[rb][cb], 0, 0, 0);
        }
    }

    // ================= norms from the diagonal =================
    if (wr == wc) {
#pragma unroll
        for (int rb = 0; rb < 4; ++rb) {
            if (hi == (lo >> 2)) {             // lane holds diag elem (lo, lo) of subtile
                const int reg = lo & 3;
                const f32x4 a = acc[rb][rb];
                const float d = (reg == 0) ? a[0] : (reg == 1) ? a[1] : (reg == 2) ? a[2] : a[3];
                norms[wr * 64 + rb * 16 + lo] = sqrtf(d);
            }
        }
    }
    if (t < Nn) {
        const float u = logits[(size_t)b * Nn + t];
        uvec[t] = u;
        lgv[t]  = u;
    }
    __syncthreads();
    if (t < Nn) invn[t] = 1.0f / norms[t];
    __syncthreads();

    // ================= P = (C * invn_r * invn_c) * 0.5*(W[r][c]+W[c][r]) =================
#pragma unroll
    for (int rb = 0; rb < 4; ++rb) {
        const int rbase = wr * 64 + rb * 16 + hi * 4;
        const float4 ir4 = *reinterpret_cast<const float4*>(&invn[rbase]);  // broadcast read
        const float ir[4] = {ir4.x, ir4.y, ir4.z, ir4.w};
#pragma unroll
        for (int cb = 0; cb < 4; ++cb) {
            const int col = wc * 64 + cb * 16 + lo;
            const float ic = invn[col];
#pragma unroll
            for (int r = 0; r < 4; ++r) {
                const int row = rbase + r;
                const float wsym = 0.5f * (W[row * Nn + col] + W[col * Nn + row]);
                acc[rb][cb][r] = acc[rb][cb][r] * ir[r] * ic * wsym;
            }
        }
    }

    // ================= 10 mean-field iterations =================
    // P is symmetric -> e[col] = sum_rows P[row][col]*s[row]; rows reduce in-lane
    // over regs, + butterfly over the 4 hi-groups, + LDS cross-wave over wr.
    for (int itr = 0; itr < NITER; ++itr) {
        if (t < Nn) {
            const float x = lgv[t];
            svec[t] = 2.f / (1.f + __expf(-x)) - 1.f;
        }
        __syncthreads();

        float ep[4] = {0.f, 0.f, 0.f, 0.f};
#pragma unroll
        for (int rb = 0; rb < 4; ++rb) {
            const float4 s4 = *reinterpret_cast<const float4*>(&svec[wr * 64 + rb * 16 + hi * 4]);
#pragma unroll
            for (int cb = 0; cb < 4; ++cb)
                ep[cb] += acc[rb][cb][0] * s4.x + acc[rb][cb][1] * s4.y
                        + acc[rb][cb][2] * s4.z + acc[rb][cb][3] * s4.w;
        }
#pragma unroll
        for (int cb = 0; cb < 4; ++cb) {
            ep[cb] += __shfl_xor(ep[cb], 16);
            ep[cb] += __shfl_xor(ep[cb], 32);
        }
        if (lane < 16) {
#pragma unroll
            for (int cb = 0; cb < 4; ++cb)
                part[wr][wc * 64 + cb * 16 + lane] = ep[cb];
        }
        __syncthreads();
        if (t < Nn)
            lgv[t] = uvec[t] + part[0][t] + part[1][t] + part[2][t] + part[3][t];
        // no trailing barrier needed: next iter's part writes are after the next
        // __syncthreads(); lgv[t] is read only by the thread that wrote it.
    }

    if (t < Nn) out[(size_t)b * Nn + t] = lgv[t];
}

extern "C" void kernel_launch(void* const* d_in, const int* in_sizes, int n_in,
                              void* d_out, int out_size, void* d_ws, size_t ws_size,
                              hipStream_t stream) {
    const float* feats  = (const float*)d_in[0];
    const float* logits = (const float*)d_in[1];
    const float* W      = (const float*)d_in[2];
    float* out = (float*)d_out;

    crf_mfma<<<dim3(Bb), dim3(1024), 0, stream>>>(feats, logits, W, out);
}